// Round 8
// baseline (848.303 us; speedup 1.0000x reference)
//
#include <hip/hip_runtime.h>
#include <hip/hip_bf16.h>

#define N_ROWS 65536
#define DIM    2048
#define NEXP   8
#define TOPK   2
#define STEPS  4                   // 4 steps x 2 chunks x 64 lanes x f4 = 2048 cols
#define BLOCK  1024                // 16 waves/block
#define GRID   512                 // 2 blocks/CU; 8192 waves; 8 rows/wave exact

typedef float f4 __attribute__((ext_vector_type(4)));

// R7 post-mortem: 4.96 TB/s vs 6.29 copy ceiling; VALU/LDS/vmem issue all
// <20% subscribed -> DRAM page locality is the suspect. This round: one row
// per wave (halves concurrent streams 16384->8192) visited in 4 bursts of
// 2 KB contiguous (2 adjacent dwordx4 per step) instead of 8 visits of 1 KB
// across 2 rows. launch_bounds(1024,8) hard-caps VGPR at 64 so occupancy
// stays 2 blocks/CU = 32 waves/CU.
__global__ __launch_bounds__(BLOCK, 8) void moe_router_kernel(
    const float* __restrict__ x,
    const float* __restrict__ W,
    const float* __restrict__ b,
    float* __restrict__ out_vals,   // [N, 2] f32
    float* __restrict__ out_idx,    // [N, 2] written as f32
    float* __restrict__ out_x)      // [N, D] f32 (pass-through copy)
{
    __shared__ float sW[NEXP * DIM];   // 64 KiB

    const f4* W4 = (const f4*)W;
    f4* sW4 = (f4*)sW;
    for (int i = threadIdx.x; i < NEXP * DIM / 4; i += BLOCK)
        sW4[i] = W4[i];
    __syncthreads();

    const int lane   = threadIdx.x & 63;
    const int wave   = (int)((blockIdx.x * BLOCK + threadIdx.x) >> 6);
    const int nwaves = (GRID * BLOCK) >> 6;   // 8192

    const f4* x4 = (const f4*)x;
    f4* ox4 = (f4*)out_x;
    const int row_f4 = DIM / 4;   // 512 float4s per row

    for (int row = wave; row < N_ROWS; row += nwaves) {
        const size_t base = (size_t)row * row_f4 + lane;

        float acc[NEXP];
#pragma unroll
        for (int e = 0; e < NEXP; ++e) acc[e] = 0.0f;

        // prologue: step 0's 2-KB burst in flight (two adjacent 1-KB wave loads)
        f4 x0 = x4[base];
        f4 x1 = x4[base + 64];

#pragma unroll 2
        for (int s = 0; s < STEPS; ++s) {
            const int col = s * 128;   // f4 column of this step

            // prefetch next step's 2-KB burst, back-to-back addresses
            f4 n0, n1;
            if (s + 1 < STEPS) {
                n0 = x4[base + col + 128];
                n1 = x4[base + col + 192];
            }

            // store current burst (fused pass-through copy), also back-to-back
            ox4[base + col]      = x0;
            ox4[base + col + 64] = x1;

#pragma unroll
            for (int e = 0; e < NEXP; ++e) {
                const f4 w0 = sW4[e * row_f4 + col + lane];
                const f4 w1 = sW4[e * row_f4 + col + 64 + lane];
                acc[e] += x0.x * w0.x + x0.y * w0.y + x0.z * w0.z + x0.w * w0.w
                        + x1.x * w1.x + x1.y * w1.y + x1.z * w1.z + x1.w * w1.w;
            }

            x0 = n0;
            x1 = n1;
        }

        // Wave-wide butterfly reduce: every lane ends with the full dot product.
#pragma unroll
        for (int e = 0; e < NEXP; ++e) {
            float v = acc[e];
            v += __shfl_xor(v, 32, 64);
            v += __shfl_xor(v, 16, 64);
            v += __shfl_xor(v, 8, 64);
            v += __shfl_xor(v, 4, 64);
            v += __shfl_xor(v, 2, 64);
            v += __shfl_xor(v, 1, 64);
            acc[e] = v;
        }

        // Lane 0 finishes the row: bias, softmax over 8, top-2.
        if (lane == 0) {
            float lg[NEXP];
#pragma unroll
            for (int e = 0; e < NEXP; ++e) lg[e] = acc[e] + b[e];

            float mx = lg[0];
#pragma unroll
            for (int e = 1; e < NEXP; ++e) mx = fmaxf(mx, lg[e]);

            float p[NEXP];
            float sum = 0.0f;
#pragma unroll
            for (int e = 0; e < NEXP; ++e) { p[e] = __expf(lg[e] - mx); sum += p[e]; }
            const float inv = 1.0f / sum;

            // top-1: strict > keeps the lowest index on ties (jax.lax.top_k order)
            int i1 = 0;
#pragma unroll
            for (int e = 1; e < NEXP; ++e) if (lg[e] > lg[i1]) i1 = e;
            // top-2: lowest-index-first among the rest
            int i2 = (i1 == 0) ? 1 : 0;
#pragma unroll
            for (int e = 0; e < NEXP; ++e)
                if (e != i1 && e != i2 && lg[e] > lg[i2]) i2 = e;

            out_vals[row * 2 + 0] = p[i1] * inv;
            out_vals[row * 2 + 1] = p[i2] * inv;
            out_idx[row * 2 + 0]  = (float)i1;
            out_idx[row * 2 + 1]  = (float)i2;
        }
    }
}

extern "C" void kernel_launch(void* const* d_in, const int* in_sizes, int n_in,
                              void* d_out, int out_size, void* d_ws, size_t ws_size,
                              hipStream_t stream) {
    const float* x = (const float*)d_in[0];
    const float* W = (const float*)d_in[1];
    const float* b = (const float*)d_in[2];

    float* out = (float*)d_out;
    float* out_vals = out;                       // N*2
    float* out_idx  = out + (size_t)N_ROWS * 2;  // N*2
    float* out_x    = out + (size_t)N_ROWS * 4;  // N*D

    moe_router_kernel<<<GRID, BLOCK, 0, stream>>>(x, W, b, out_vals, out_idx, out_x);
}

// Round 9
// 219.772 us; speedup vs baseline: 3.8599x; 3.8599x over previous
//
#include <hip/hip_runtime.h>
#include <hip/hip_bf16.h>

#define N_ROWS 65536
#define DIM    2048
#define NEXP   8
#define TOPK   2
#define STEPS  4                   // 4 steps x 2 chunks x 64 lanes x f4 = 2048 cols
#define BLOCK  1024                // 16 waves/block
#define GRID   512                 // 2 blocks/CU; 8192 waves; 8 rows/wave exact

typedef float f4 __attribute__((ext_vector_type(4)));

// R8 structure, fixed launch bound. Twice-confirmed rule (R4, R8):
// __launch_bounds__(1024,8) -> VGPR=32 -> spill cliff (FETCH +0.7GB, WRITE +1.7GB).
// __launch_bounds__(1024,4) -> VGPR=64 -> clean. LDS 64KiB still gives
// 2 blocks/CU = 32 waves/CU. This round isolates the burst-locality variable:
// one row-stream per wave, 2KB contiguous per visit (R7: 2 streams x 1KB).
__global__ __launch_bounds__(BLOCK, 4) void moe_router_kernel(
    const float* __restrict__ x,
    const float* __restrict__ W,
    const float* __restrict__ b,
    float* __restrict__ out_vals,   // [N, 2] f32
    float* __restrict__ out_idx,    // [N, 2] written as f32
    float* __restrict__ out_x)      // [N, D] f32 (pass-through copy)
{
    __shared__ float sW[NEXP * DIM];   // 64 KiB

    const f4* W4 = (const f4*)W;
    f4* sW4 = (f4*)sW;
    for (int i = threadIdx.x; i < NEXP * DIM / 4; i += BLOCK)
        sW4[i] = W4[i];
    __syncthreads();

    const int lane   = threadIdx.x & 63;
    const int wave   = (int)((blockIdx.x * BLOCK + threadIdx.x) >> 6);
    const int nwaves = (GRID * BLOCK) >> 6;   // 8192

    const f4* x4 = (const f4*)x;
    f4* ox4 = (f4*)out_x;
    const int row_f4 = DIM / 4;   // 512 float4s per row

    for (int row = wave; row < N_ROWS; row += nwaves) {
        const size_t base = (size_t)row * row_f4 + lane;

        float acc[NEXP];
#pragma unroll
        for (int e = 0; e < NEXP; ++e) acc[e] = 0.0f;

        // prologue: step 0's 2-KB burst in flight (two adjacent 1-KB wave loads)
        f4 x0 = x4[base];
        f4 x1 = x4[base + 64];

#pragma unroll 2
        for (int s = 0; s < STEPS; ++s) {
            const int col = s * 128;   // f4 column of this step

            // prefetch next step's 2-KB burst, back-to-back addresses
            f4 n0, n1;
            if (s + 1 < STEPS) {
                n0 = x4[base + col + 128];
                n1 = x4[base + col + 192];
            }

            // store current burst (fused pass-through copy), also back-to-back
            ox4[base + col]      = x0;
            ox4[base + col + 64] = x1;

#pragma unroll
            for (int e = 0; e < NEXP; ++e) {
                const f4 w0 = sW4[e * row_f4 + col + lane];
                const f4 w1 = sW4[e * row_f4 + col + 64 + lane];
                acc[e] += x0.x * w0.x + x0.y * w0.y + x0.z * w0.z + x0.w * w0.w
                        + x1.x * w1.x + x1.y * w1.y + x1.z * w1.z + x1.w * w1.w;
            }

            x0 = n0;
            x1 = n1;
        }

        // Wave-wide butterfly reduce: every lane ends with the full dot product.
#pragma unroll
        for (int e = 0; e < NEXP; ++e) {
            float v = acc[e];
            v += __shfl_xor(v, 32, 64);
            v += __shfl_xor(v, 16, 64);
            v += __shfl_xor(v, 8, 64);
            v += __shfl_xor(v, 4, 64);
            v += __shfl_xor(v, 2, 64);
            v += __shfl_xor(v, 1, 64);
            acc[e] = v;
        }

        // Lane 0 finishes the row: bias, softmax over 8, top-2.
        if (lane == 0) {
            float lg[NEXP];
#pragma unroll
            for (int e = 0; e < NEXP; ++e) lg[e] = acc[e] + b[e];

            float mx = lg[0];
#pragma unroll
            for (int e = 1; e < NEXP; ++e) mx = fmaxf(mx, lg[e]);

            float p[NEXP];
            float sum = 0.0f;
#pragma unroll
            for (int e = 0; e < NEXP; ++e) { p[e] = __expf(lg[e] - mx); sum += p[e]; }
            const float inv = 1.0f / sum;

            // top-1: strict > keeps the lowest index on ties (jax.lax.top_k order)
            int i1 = 0;
#pragma unroll
            for (int e = 1; e < NEXP; ++e) if (lg[e] > lg[i1]) i1 = e;
            // top-2: lowest-index-first among the rest
            int i2 = (i1 == 0) ? 1 : 0;
#pragma unroll
            for (int e = 0; e < NEXP; ++e)
                if (e != i1 && e != i2 && lg[e] > lg[i2]) i2 = e;

            out_vals[row * 2 + 0] = p[i1] * inv;
            out_vals[row * 2 + 1] = p[i2] * inv;
            out_idx[row * 2 + 0]  = (float)i1;
            out_idx[row * 2 + 1]  = (float)i2;
        }
    }
}

extern "C" void kernel_launch(void* const* d_in, const int* in_sizes, int n_in,
                              void* d_out, int out_size, void* d_ws, size_t ws_size,
                              hipStream_t stream) {
    const float* x = (const float*)d_in[0];
    const float* W = (const float*)d_in[1];
    const float* b = (const float*)d_in[2];

    float* out = (float*)d_out;
    float* out_vals = out;                       // N*2
    float* out_idx  = out + (size_t)N_ROWS * 2;  // N*2
    float* out_x    = out + (size_t)N_ROWS * 4;  // N*D

    moe_router_kernel<<<GRID, BLOCK, 0, stream>>>(x, W, b, out_vals, out_idx, out_x);
}